// Round 1
// baseline (703.716 us; speedup 1.0000x reference)
//
#include <hip/hip_runtime.h>

#define NBANDS 31
#define BB 8
#define CCH 2
#define FF 2049
#define TTS 512
#define OUTC 128
#define TCH 8196
#define EPSV 1e-5f

#define KC 16
#define TTILE 64

__constant__ int c_wid[NBANDS] = {
    25,25,25,25,25,25,25,25,25,25,
    50,50,50,50,50,50,50,50,50,50,50,50,
    100,100,100,100,100,100,100,100,
    399};
__constant__ int c_start[NBANDS] = {
    0,25,50,75,100,125,150,175,200,225,
    250,300,350,400,450,500,550,600,650,700,750,800,
    850,950,1050,1150,1250,1350,1450,1550,
    1650};
// cumulative f-chunk (32 rows each) start per band; total chunks = 79
__constant__ int c_cumf[NBANDS] = {
    0,1,2,3,4,5,6,7,8,9,
    10,12,14,16,18,20,22,24,26,28,30,32,
    34,38,42,46,50,54,58,62,
    66};

// ---------------- stats: partial sums per (b, band) ----------------
__global__ __launch_bounds__(256) void stats_partial(const float* __restrict__ x,
                                                     float* __restrict__ st) {
    int bx = blockIdx.x;                 // chunk id in [0,79)
    int band = 0;
    while (band + 1 < NBANDS && bx >= c_cumf[band + 1]) band++;
    int fc = bx - c_cumf[band];
    int b  = blockIdx.y >> 1;
    int cc = blockIdx.y & 1;
    int w = c_wid[band], s = c_start[band];
    int f0 = fc * 32;
    int rows = min(32, w - f0);

    const float4* p = (const float4*)(x + ((size_t)(b * CCH + cc) * FF + (s + f0)) * (TTS * 2));
    int n4 = rows * 256;                 // rows * 1024 floats / 4
    float sum = 0.f, sq = 0.f;
    for (int i = threadIdx.x; i < n4; i += 256) {
        float4 v = p[i];
        sum += v.x + v.y + v.z + v.w;
        sq  += v.x * v.x + v.y * v.y + v.z * v.z + v.w * v.w;
    }
    __shared__ float s1[256], s2[256];
    int tid = threadIdx.x;
    s1[tid] = sum; s2[tid] = sq;
    __syncthreads();
    for (int st_ = 128; st_ > 0; st_ >>= 1) {
        if (tid < st_) { s1[tid] += s1[tid + st_]; s2[tid] += s2[tid + st_]; }
        __syncthreads();
    }
    if (tid == 0) {
        atomicAdd(&st[(b * NBANDS + band) * 2 + 0], s1[0]);
        atomicAdd(&st[(b * NBANDS + band) * 2 + 1], s2[0]);
    }
}

__global__ void finalize_stats(const float* __restrict__ st, float* __restrict__ musr) {
    int i = blockIdx.x * blockDim.x + threadIdx.x;
    if (i < BB * NBANDS) {
        int band = i % NBANDS;
        float N = 4.f * (float)c_wid[band] * (float)TTS;
        float sum = st[2 * i], sq = st[2 * i + 1];
        float mu = sum / N;
        float var = sq / N - mu * mu;
        musr[2 * i]     = mu;
        musr[2 * i + 1] = rsqrtf(var + EPSV);
    }
}

// --------- W prep: wgam[band,o]=sum W*gamma ; wcb[band,o]=sum W*beta + bias ---------
__global__ __launch_bounds__(256) void wprep(const float* __restrict__ W,
                                             const float* __restrict__ gamma,
                                             const float* __restrict__ beta,
                                             const float* __restrict__ bias,
                                             float* __restrict__ wgam,
                                             float* __restrict__ wcb) {
    int band = blockIdx.x;
    int off = 4 * c_start[band];
    int ch  = 4 * c_wid[band];
    int o = blockIdx.y * 16 + (threadIdx.x >> 4);
    int lane = threadIdx.x & 15;
    const float* wrow = W + (size_t)o * TCH + off;
    float sg = 0.f, sb = 0.f;
    for (int c = lane; c < ch; c += 16) {
        float wv = wrow[c];
        sg += wv * gamma[off + c];
        sb += wv * beta[off + c];
    }
    for (int m = 8; m; m >>= 1) {
        sg += __shfl_down(sg, m, 16);
        sb += __shfl_down(sb, m, 16);
    }
    if (lane == 0) {
        wgam[band * OUTC + o] = sg;
        wcb[band * OUTC + o]  = sb + bias[band * OUTC + o];
    }
}

// ---------------- fused normalize + GEMM ----------------
// grid: (T/TTILE, NBANDS, B), block 256
// y[b,o,band,t] = rs*(sum_c (W*gamma)[o,c]*h[c,t] - mu*wgam[band,o]) + wcb[band,o]
__global__ __launch_bounds__(256) void gemm_band(const float* __restrict__ x,
                                                 const float* __restrict__ W,
                                                 const float* __restrict__ gamma,
                                                 const float* __restrict__ musr,
                                                 const float* __restrict__ wgam,
                                                 const float* __restrict__ wcb,
                                                 float* __restrict__ out) {
    const int tt0  = blockIdx.x * TTILE;
    const int band = blockIdx.y;
    const int b    = blockIdx.z;
    const int w   = c_wid[band];
    const int s   = c_start[band];
    const int off = 4 * c_start[band];
    const int K2  = 2 * w;               // paired-k dimension; pairs (k', 2w+k')

    __shared__ float hA[KC][TTILE];
    __shared__ float hB[KC][TTILE];
    __shared__ float wA[KC][OUTC + 1];
    __shared__ float wB[KC][OUTC + 1];

    const int tid = threadIdx.x;
    const int tx = tid & 15;             // t-group: t = tx*4 .. tx*4+3
    const int ty = tid >> 4;             // o-group: o = ty*8 .. ty*8+7

    float acc[8][4];
#pragma unroll
    for (int i = 0; i < 8; ++i)
#pragma unroll
        for (int j = 0; j < 4; ++j) acc[i][j] = 0.f;

    const float* xb = x + (size_t)b * CCH * FF * TTS * 2;

    for (int k0 = 0; k0 < K2; k0 += KC) {
        // stage h: k' = k0+kk -> channels c0 = k' (ri=0), c1 = 2w+k' (ri=1)
#pragma unroll
        for (int it = 0; it < 4; ++it) {
            int idx = it * 256 + tid;    // 0..1023 = 16kk x 64t
            int kk = idx >> 6;
            int t  = idx & 63;
            int k  = k0 + kk;
            float2 v = make_float2(0.f, 0.f);
            if (k < K2) {
                int cc = (k >= w) ? 1 : 0;
                int f  = k - cc * w;
                v = *(const float2*)(xb + ((size_t)(cc * FF + s + f)) * (TTS * 2) + (tt0 + t) * 2);
            }
            hA[kk][t] = v.x;
            hB[kk][t] = v.y;
        }
        // stage W*gamma: wA[kk][o] = Wg[o, off+k], wB[kk][o] = Wg[o, off+2w+k]
#pragma unroll
        for (int it = 0; it < 8; ++it) {
            int idx = it * 256 + tid;    // 0..2047 = 128o x 16kk
            int kk = idx & 15;
            int o  = idx >> 4;
            int k  = k0 + kk;
            float a = 0.f, bv = 0.f;
            if (k < K2) {
                a  = W[(size_t)o * TCH + off + k]      * gamma[off + k];
                bv = W[(size_t)o * TCH + off + K2 + k] * gamma[off + K2 + k];
            }
            wA[kk][o] = a;
            wB[kk][o] = bv;
        }
        __syncthreads();
#pragma unroll
        for (int kk = 0; kk < KC; ++kk) {
            float4 ha = *(const float4*)&hA[kk][tx * 4];
            float4 hb = *(const float4*)&hB[kk][tx * 4];
#pragma unroll
            for (int i = 0; i < 8; ++i) {
                float wa = wA[kk][ty * 8 + i];
                float wb = wB[kk][ty * 8 + i];
                acc[i][0] += wa * ha.x + wb * hb.x;
                acc[i][1] += wa * ha.y + wb * hb.y;
                acc[i][2] += wa * ha.z + wb * hb.z;
                acc[i][3] += wa * ha.w + wb * hb.w;
            }
        }
        __syncthreads();
    }

    const float mu = musr[(b * NBANDS + band) * 2 + 0];
    const float rs = musr[(b * NBANDS + band) * 2 + 1];
#pragma unroll
    for (int i = 0; i < 8; ++i) {
        int o = ty * 8 + i;
        float wg = wgam[band * OUTC + o];
        float cb = wcb[band * OUTC + o];
        float4 r;
        r.x = rs * (acc[i][0] - mu * wg) + cb;
        r.y = rs * (acc[i][1] - mu * wg) + cb;
        r.z = rs * (acc[i][2] - mu * wg) + cb;
        r.w = rs * (acc[i][3] - mu * wg) + cb;
        *(float4*)&out[(((size_t)b * OUTC + o) * NBANDS + band) * TTS + tt0 + tx * 4] = r;
    }
}

extern "C" void kernel_launch(void* const* d_in, const int* in_sizes, int n_in,
                              void* d_out, int out_size, void* d_ws, size_t ws_size,
                              hipStream_t stream) {
    const float* x     = (const float*)d_in[0];
    const float* gamma = (const float*)d_in[1];
    const float* beta  = (const float*)d_in[2];
    const float* W     = (const float*)d_in[3];
    const float* bias  = (const float*)d_in[4];
    float* out = (float*)d_out;
    float* ws  = (float*)d_ws;

    float* st_part = ws;          // 496 floats (sum, sumsq per (b,band))
    float* musr    = ws + 512;    // 496 floats (mu, rs)
    float* wgam    = ws + 1024;   // 3968 floats
    float* wcb     = ws + 5120;   // 3968 floats

    hipMemsetAsync(st_part, 0, (BB * NBANDS * 2) * sizeof(float), stream);
    stats_partial<<<dim3(79, BB * 2), 256, 0, stream>>>(x, st_part);
    finalize_stats<<<1, 256, 0, stream>>>(st_part, musr);
    wprep<<<dim3(NBANDS, OUTC / 16), 256, 0, stream>>>(W, gamma, beta, bias, wgam, wcb);
    gemm_band<<<dim3(TTS / TTILE, NBANDS, BB), 256, 0, stream>>>(x, W, gamma, musr, wgam, wcb, out);
}

// Round 2
// 190.366 us; speedup vs baseline: 3.6966x; 3.6966x over previous
//
#include <hip/hip_runtime.h>
#include <hip/hip_bf16.h>

typedef __attribute__((ext_vector_type(8))) short short8;
typedef __attribute__((ext_vector_type(8))) unsigned short ushort8;
typedef __attribute__((ext_vector_type(4))) float f32x4;

#define NBANDS 31
#define BB 8
#define CCH 2
#define FF 2049
#define TTS 512
#define OUTC 128
#define TCH 8196
#define EPSV 1e-5f
#define LDA 40   // LDS row stride (elements): 80B -> bank stride 20, <=2-way conflicts

__constant__ int c_wid[NBANDS] = {
    25,25,25,25,25,25,25,25,25,25,
    50,50,50,50,50,50,50,50,50,50,50,50,
    100,100,100,100,100,100,100,100,
    399};
__constant__ int c_start[NBANDS] = {
    0,25,50,75,100,125,150,175,200,225,
    250,300,350,400,450,500,550,600,650,700,750,800,
    850,950,1050,1150,1250,1350,1450,1550,
    1650};
__constant__ int c_cumf[NBANDS] = {
    0,1,2,3,4,5,6,7,8,9,
    10,12,14,16,18,20,22,24,26,28,30,32,
    34,38,42,46,50,54,58,62,
    66};
// K padded to multiple of 32 (4w rounded up)
__constant__ int c_kpad[NBANDS] = {
    128,128,128,128,128,128,128,128,128,128,
    224,224,224,224,224,224,224,224,224,224,224,224,
    416,416,416,416,416,416,416,416,
    1600};
// element base of each band's packed Wgamma panel (o-major, [o][Kpad])
__constant__ int c_kbase[NBANDS] = {
    0,16384,32768,49152,65536,81920,98304,114688,131072,147456,
    163840,192512,221184,249856,278528,307200,335872,364544,393216,421888,450560,479232,
    507904,561152,614400,667648,720896,774144,827392,880640,
    933888};
// heavy-first dispatch order (descending K)
__constant__ int c_order[NBANDS] = {
    30,22,23,24,25,26,27,28,29,
    10,11,12,13,14,15,16,17,18,19,20,21,
    0,1,2,3,4,5,6,7,8,9};

__device__ inline unsigned short f2bf(float f) {
    __hip_bfloat16 h = __float2bfloat16(f);
    unsigned short u;
    __builtin_memcpy(&u, &h, 2);
    return u;
}

// ---------------- stats: partial sums per (b, band) ----------------
__global__ __launch_bounds__(256) void stats_partial(const float* __restrict__ x,
                                                     float* __restrict__ st) {
    int bx = blockIdx.x;                 // chunk id in [0,79)
    int band = 0;
    while (band + 1 < NBANDS && bx >= c_cumf[band + 1]) band++;
    int fc = bx - c_cumf[band];
    int b  = blockIdx.y >> 1;
    int cc = blockIdx.y & 1;
    int w = c_wid[band], s = c_start[band];
    int f0 = fc * 32;
    int rows = min(32, w - f0);

    const float4* p = (const float4*)(x + ((size_t)(b * CCH + cc) * FF + (s + f0)) * (TTS * 2));
    int n4 = rows * 256;
    float sum = 0.f, sq = 0.f;
    for (int i = threadIdx.x; i < n4; i += 256) {
        float4 v = p[i];
        sum += v.x + v.y + v.z + v.w;
        sq  += v.x * v.x + v.y * v.y + v.z * v.z + v.w * v.w;
    }
    __shared__ float s1[256], s2[256];
    int tid = threadIdx.x;
    s1[tid] = sum; s2[tid] = sq;
    __syncthreads();
    for (int st_ = 128; st_ > 0; st_ >>= 1) {
        if (tid < st_) { s1[tid] += s1[tid + st_]; s2[tid] += s2[tid + st_]; }
        __syncthreads();
    }
    if (tid == 0) {
        atomicAdd(&st[(b * NBANDS + band) * 2 + 0], s1[0]);
        atomicAdd(&st[(b * NBANDS + band) * 2 + 1], s2[0]);
    }
}

__global__ void finalize_stats(const float* __restrict__ st, float* __restrict__ musr) {
    int i = blockIdx.x * blockDim.x + threadIdx.x;
    if (i < BB * NBANDS) {
        int band = i % NBANDS;
        float N = 4.f * (float)c_wid[band] * (float)TTS;
        float sum = st[2 * i], sq = st[2 * i + 1];
        float mu = sum / N;
        float var = sq / N - mu * mu;
        musr[2 * i]     = mu;
        musr[2 * i + 1] = rsqrtf(var + EPSV);
    }
}

// --------- wgam[band,o]=sum W*gamma ; wcb[band,o]=sum W*beta + bias ---------
__global__ __launch_bounds__(256) void wprep(const float* __restrict__ W,
                                             const float* __restrict__ gamma,
                                             const float* __restrict__ beta,
                                             const float* __restrict__ bias,
                                             float* __restrict__ wgam,
                                             float* __restrict__ wcb) {
    int band = blockIdx.x;
    int off = 4 * c_start[band];
    int ch  = 4 * c_wid[band];
    int o = blockIdx.y * 16 + (threadIdx.x >> 4);
    int lane = threadIdx.x & 15;
    const float* wrow = W + (size_t)o * TCH + off;
    float sg = 0.f, sb = 0.f;
    for (int c = lane; c < ch; c += 16) {
        float wv = wrow[c];
        sg += wv * gamma[off + c];
        sb += wv * beta[off + c];
    }
    for (int m = 8; m; m >>= 1) {
        sg += __shfl_down(sg, m, 16);
        sb += __shfl_down(sb, m, 16);
    }
    if (lane == 0) {
        wgam[band * OUTC + o] = sg;
        wcb[band * OUTC + o]  = sb + bias[band * OUTC + o];
    }
}

// --------- pack W*gamma into bf16 panels, K permuted so k = 2*(cc*w+f)+ri ---------
__global__ __launch_bounds__(256) void wprep2(const float* __restrict__ W,
                                              const float* __restrict__ gamma,
                                              unsigned short* __restrict__ wgP) {
    int band = blockIdx.x;
    int w = c_wid[band];
    int s4 = 4 * c_start[band];
    int Kpad = c_kpad[band];
    int base = c_kbase[band];
    int K4 = 4 * w;
    int N = OUTC * Kpad;
    for (int idx = blockIdx.y * blockDim.x + threadIdx.x; idx < N;
         idx += gridDim.y * blockDim.x) {
        int o = idx / Kpad;
        int k = idx - o * Kpad;
        float val = 0.f;
        if (k < K4) {
            int ri = k & 1, p = k >> 1;
            int cc = (p >= w) ? 1 : 0;
            int f = p - cc * w;
            int c = s4 + ri * 2 * w + cc * w + f;
            val = W[(size_t)o * TCH + c] * gamma[c];
        }
        wgP[base + idx] = f2bf(val);
    }
}

// ---------------- MFMA GEMM: Y[o,t] = Wg[o,:]*h[:,t], norm fused in epilogue ----------------
// grid (8 ttiles, 31 bands, 8 b), 256 threads = 4 waves (2x2 of 64x32 wave tiles)
__global__ __launch_bounds__(256) void gemm_mfma(const float* __restrict__ x,
                                                 const unsigned short* __restrict__ wgP,
                                                 const float* __restrict__ musr,
                                                 const float* __restrict__ wgam,
                                                 const float* __restrict__ wcb,
                                                 float* __restrict__ out) {
    const int band = c_order[blockIdx.y];
    const int b    = blockIdx.z;
    const int tt0  = blockIdx.x * 64;
    const int w    = c_wid[band];
    const int s    = c_start[band];
    const int Kpad = c_kpad[band];
    const int K4   = 4 * w;
    const int nch  = Kpad >> 5;
    const unsigned short* wgA = wgP + c_kbase[band];

    __shared__ unsigned short lA[2][128 * LDA];
    __shared__ unsigned short lB[2][64 * LDA];

    const int tid  = threadIdx.x;
    const int lane = tid & 63;
    const int wave = tid >> 6;
    const int wm   = wave >> 1;   // 0..1 : o-half
    const int wn   = wave & 1;    // 0..1 : t-half
    const int l15  = lane & 15;
    const int lg   = lane >> 4;

    const float* xb = x + (size_t)b * (CCH * FF * TTS * 2);

    f32x4 acc[4][2] = {};

#define STAGE(k0, buf) do {                                                          \
    _Pragma("unroll")                                                                \
    for (int it = 0; it < 2; ++it) {                                                 \
        int idx = it * 256 + tid;                                                    \
        int o = idx >> 2, g = idx & 3;                                               \
        ushort8 av = *(const ushort8*)(wgA + (size_t)o * Kpad + (k0) + g * 8);       \
        *(ushort8*)&lA[buf][o * LDA + g * 8] = av;                                   \
    }                                                                                \
    _Pragma("unroll")                                                                \
    for (int it = 0; it < 4; ++it) {                                                 \
        int idx = it * 256 + tid;                                                    \
        int t = idx & 63, pl = idx >> 6;                                             \
        int knew = (k0) + 2 * pl;                                                    \
        float2 v = make_float2(0.f, 0.f);                                            \
        if (knew < K4) {                                                             \
            int p = knew >> 1;                                                       \
            int cc = (p >= w) ? 1 : 0;                                               \
            int f = p - cc * w;                                                      \
            v = *(const float2*)(xb + ((size_t)(cc * FF + s + f)) * (TTS * 2)        \
                                 + (size_t)(tt0 + t) * 2);                           \
        }                                                                            \
        ushort2 u2 = make_ushort2(f2bf(v.x), f2bf(v.y));                             \
        *(ushort2*)&lB[buf][t * LDA + 2 * pl] = u2;                                  \
    }                                                                                \
} while (0)

    STAGE(0, 0);
    __syncthreads();
    int cur = 0;
    for (int c = 0; c < nch; ++c) {
        if (c + 1 < nch) STAGE((c + 1) * 32, cur ^ 1);
        short8 af[4];
#pragma unroll
        for (int m = 0; m < 4; ++m)
            af[m] = *(const short8*)&lA[cur][(wm * 64 + m * 16 + l15) * LDA + lg * 8];
        short8 bfv[2];
#pragma unroll
        for (int n = 0; n < 2; ++n)
            bfv[n] = *(const short8*)&lB[cur][(wn * 32 + n * 16 + l15) * LDA + lg * 8];
#pragma unroll
        for (int m = 0; m < 4; ++m)
#pragma unroll
            for (int n = 0; n < 2; ++n)
                acc[m][n] = __builtin_amdgcn_mfma_f32_16x16x32_bf16(af[m], bfv[n], acc[m][n], 0, 0, 0);
        __syncthreads();
        cur ^= 1;
    }
#undef STAGE

    const float mu = musr[(b * NBANDS + band) * 2 + 0];
    const float rs = musr[(b * NBANDS + band) * 2 + 1];
#pragma unroll
    for (int m = 0; m < 4; ++m) {
#pragma unroll
        for (int r = 0; r < 4; ++r) {
            int o = wm * 64 + m * 16 + lg * 4 + r;
            float wg = wgam[band * OUTC + o];
            float cb = wcb[band * OUTC + o];
            size_t rowoff = (((size_t)b * OUTC + o) * NBANDS + band) * TTS;
#pragma unroll
            for (int n = 0; n < 2; ++n) {
                int t = tt0 + wn * 32 + n * 16 + l15;
                out[rowoff + t] = rs * (acc[m][n][r] - mu * wg) + cb;
            }
        }
    }
}

extern "C" void kernel_launch(void* const* d_in, const int* in_sizes, int n_in,
                              void* d_out, int out_size, void* d_ws, size_t ws_size,
                              hipStream_t stream) {
    const float* x     = (const float*)d_in[0];
    const float* gamma = (const float*)d_in[1];
    const float* beta  = (const float*)d_in[2];
    const float* W     = (const float*)d_in[3];
    const float* bias  = (const float*)d_in[4];
    float* out = (float*)d_out;
    float* ws  = (float*)d_ws;

    float* st_part = ws;            // 496 floats
    float* musr    = ws + 512;      // 496 floats
    float* wgam    = ws + 1024;     // 3968 floats
    float* wcb     = ws + 5120;     // 3968 floats
    unsigned short* wgP = (unsigned short*)(ws + 9216);  // 1138688 bf16 = 2.28 MB

    hipMemsetAsync(st_part, 0, (BB * NBANDS * 2) * sizeof(float), stream);
    stats_partial<<<dim3(79, BB * 2), 256, 0, stream>>>(x, st_part);
    finalize_stats<<<1, 256, 0, stream>>>(st_part, musr);
    wprep<<<dim3(NBANDS, OUTC / 16), 256, 0, stream>>>(W, gamma, beta, bias, wgam, wcb);
    wprep2<<<dim3(NBANDS, 32), 256, 0, stream>>>(W, gamma, wgP);
    gemm_mfma<<<dim3(TTS / 64, NBANDS, BB), 256, 0, stream>>>(x, wgP, musr, wgam, wcb, out);
}

// Round 3
// 135.830 us; speedup vs baseline: 5.1809x; 1.4015x over previous
//
#include <hip/hip_runtime.h>
#include <hip/hip_bf16.h>

typedef __attribute__((ext_vector_type(8))) short short8;
typedef __attribute__((ext_vector_type(4))) float f32x4;

#define NBANDS 31
#define BB 8
#define CCH 2
#define FF 2049
#define TTS 512
#define OUTC 128
#define TCH 8196
#define EPSV 1e-5f

__constant__ int c_wid[NBANDS] = {
    25,25,25,25,25,25,25,25,25,25,
    50,50,50,50,50,50,50,50,50,50,50,50,
    100,100,100,100,100,100,100,100,
    399};
__constant__ int c_start[NBANDS] = {
    0,25,50,75,100,125,150,175,200,225,
    250,300,350,400,450,500,550,600,650,700,750,800,
    850,950,1050,1150,1250,1350,1450,1550,
    1650};
__constant__ int c_cumf[NBANDS] = {
    0,1,2,3,4,5,6,7,8,9,
    10,12,14,16,18,20,22,24,26,28,30,32,
    34,38,42,46,50,54,58,62,
    66};
// K padded to multiple of 64
__constant__ int c_kpad[NBANDS] = {
    128,128,128,128,128,128,128,128,128,128,
    256,256,256,256,256,256,256,256,256,256,256,256,
    448,448,448,448,448,448,448,448,
    1600};
// element base of each band's packed (swizzled, chunk-major) Wgamma panel
__constant__ int c_kbase[NBANDS] = {
    0,16384,32768,49152,65536,81920,98304,114688,131072,147456,
    163840,196608,229376,262144,294912,327680,360448,393216,425984,458752,491520,524288,
    557056,614400,671744,729088,786432,843776,901120,958464,
    1015808};
// heavy-first dispatch order (descending K)
__constant__ int c_order[NBANDS] = {
    30,22,23,24,25,26,27,28,29,
    10,11,12,13,14,15,16,17,18,19,20,21,
    0,1,2,3,4,5,6,7,8,9};

__device__ inline unsigned short f2bf(float f) {
    __hip_bfloat16 h = __float2bfloat16(f);
    unsigned short u;
    __builtin_memcpy(&u, &h, 2);
    return u;
}

__device__ inline void gload_lds16(const void* g, void* l) {
    __builtin_amdgcn_global_load_lds((const __attribute__((address_space(1))) void*)g,
                                     (__attribute__((address_space(3))) void*)l, 16, 0, 0);
}

// ---------------- stats: partial sums per (b, band) ----------------
__global__ __launch_bounds__(256) void stats_partial(const float* __restrict__ x,
                                                     float* __restrict__ st) {
    int bx = blockIdx.x;                 // chunk id in [0,79)
    int band = 0;
    while (band + 1 < NBANDS && bx >= c_cumf[band + 1]) band++;
    int fc = bx - c_cumf[band];
    int b  = blockIdx.y >> 1;
    int cc = blockIdx.y & 1;
    int w = c_wid[band], s = c_start[band];
    int f0 = fc * 32;
    int rows = min(32, w - f0);

    const float4* p = (const float4*)(x + ((size_t)(b * CCH + cc) * FF + (s + f0)) * (TTS * 2));
    int n4 = rows * 256;
    float sum = 0.f, sq = 0.f;
    for (int i = threadIdx.x; i < n4; i += 256) {
        float4 v = p[i];
        sum += v.x + v.y + v.z + v.w;
        sq  += v.x * v.x + v.y * v.y + v.z * v.z + v.w * v.w;
    }
    __shared__ float s1[256], s2[256];
    int tid = threadIdx.x;
    s1[tid] = sum; s2[tid] = sq;
    __syncthreads();
    for (int st_ = 128; st_ > 0; st_ >>= 1) {
        if (tid < st_) { s1[tid] += s1[tid + st_]; s2[tid] += s2[tid + st_]; }
        __syncthreads();
    }
    if (tid == 0) {
        atomicAdd(&st[(b * NBANDS + band) * 2 + 0], s1[0]);
        atomicAdd(&st[(b * NBANDS + band) * 2 + 1], s2[0]);
    }
}

__global__ void finalize_stats(const float* __restrict__ st, float* __restrict__ musr) {
    int i = blockIdx.x * blockDim.x + threadIdx.x;
    if (i < BB * NBANDS) {
        int band = i % NBANDS;
        float N = 4.f * (float)c_wid[band] * (float)TTS;
        float sum = st[2 * i], sq = st[2 * i + 1];
        float mu = sum / N;
        float var = sq / N - mu * mu;
        musr[2 * i]     = mu;
        musr[2 * i + 1] = rsqrtf(var + EPSV);
    }
}

// --------- wgam[band,o]=sum W*gamma ; wcb[band,o]=sum W*beta + bias ---------
__global__ __launch_bounds__(256) void wprep(const float* __restrict__ W,
                                             const float* __restrict__ gamma,
                                             const float* __restrict__ beta,
                                             const float* __restrict__ bias,
                                             float* __restrict__ wgam,
                                             float* __restrict__ wcb) {
    int band = blockIdx.x;
    int off = 4 * c_start[band];
    int ch  = 4 * c_wid[band];
    int o = blockIdx.y * 16 + (threadIdx.x >> 4);
    int lane = threadIdx.x & 15;
    const float* wrow = W + (size_t)o * TCH + off;
    float sg = 0.f, sb = 0.f;
    for (int c = lane; c < ch; c += 16) {
        float wv = wrow[c];
        sg += wv * gamma[off + c];
        sb += wv * beta[off + c];
    }
    for (int m = 8; m; m >>= 1) {
        sg += __shfl_down(sg, m, 16);
        sb += __shfl_down(sb, m, 16);
    }
    if (lane == 0) {
        wgam[band * OUTC + o] = sg;
        wcb[band * OUTC + o]  = sb + bias[band * OUTC + o];
    }
}

// --------- pack W*gamma into bf16 panels: chunk-major [c][o][64], slot-XOR swizzled,
// K permuted so k = 2*(cc*w+f)+ri ---------
__global__ __launch_bounds__(256) void wprep2(const float* __restrict__ W,
                                              const float* __restrict__ gamma,
                                              unsigned short* __restrict__ wgP) {
    int band = blockIdx.x;
    int w = c_wid[band];
    int s4 = 4 * c_start[band];
    int Kpad = c_kpad[band];
    int base = c_kbase[band];
    int K4 = 4 * w;
    int N = OUTC * Kpad;
    for (int idx = blockIdx.y * blockDim.x + threadIdx.x; idx < N;
         idx += gridDim.y * blockDim.x) {
        int o = idx / Kpad;
        int k = idx - o * Kpad;
        float val = 0.f;
        if (k < K4) {
            int ri = k & 1, p = k >> 1;
            int cc = (p >= w) ? 1 : 0;
            int f = p - cc * w;
            int c = s4 + ri * 2 * w + cc * w + f;
            val = W[(size_t)o * TCH + c] * gamma[c];
        }
        int slot = (k >> 3) & 7;
        int pos = (k >> 6) * 8192 + o * 64 + ((slot ^ (o & 7)) * 8) + (k & 7);
        wgP[base + pos] = f2bf(val);
    }
}

// ---------------- MFMA GEMM: Y[o,t] = Wg[o,:]*h[:,t], norm fused in epilogue ----------------
// grid (16 = 8b x 2 ttile, 31 bands), 512 threads = 8 waves, each wave: M=128 x N=32
__global__ __launch_bounds__(512) void gemm_mfma(const float* __restrict__ x,
                                                 const unsigned short* __restrict__ wgP,
                                                 const float* __restrict__ musr,
                                                 const float* __restrict__ wgam,
                                                 const float* __restrict__ wcb,
                                                 float* __restrict__ out) {
    const int band = c_order[blockIdx.y];
    const int b    = blockIdx.x >> 1;
    const int tt0  = (blockIdx.x & 1) * 256;
    const int w    = c_wid[band];
    const int s    = c_start[band];
    const int Kpad = c_kpad[band];
    const int nch  = Kpad >> 6;
    const unsigned short* wgA = wgP + c_kbase[band];

    __shared__ unsigned short lA[2][8192];   // 2 x 16KB: [o=128][k=64], slot-swizzled

    const int tid  = threadIdx.x;
    const int lane = tid & 63;
    const int wv   = tid >> 6;          // wave id -> t-block of 32
    const int l15  = lane & 15;
    const int lg   = lane >> 4;         // 0..3

    const float* xb = x + (size_t)b * (CCH * FF * TTS * 2);
    // per-lane t column (float index) for B loads: t = tt0 + wv*32 + nf*16 + l15
    const float* colbase = xb + (size_t)(tt0 + wv * 32 + l15) * 2;

    f32x4 acc[8][2] = {};

    // stage chunk c into buffer buf (16KB via global_load_lds dwordx4, 2 per thread)
#define STAGE(c, buf) do {                                                     \
    const unsigned short* srcc = wgA + (size_t)(c) * 8192;                     \
    gload_lds16(srcc + tid * 8,        &lA[buf][tid * 8]);                     \
    gload_lds16(srcc + 4096 + tid * 8, &lA[buf][4096 + tid * 8]);              \
} while (0)

    STAGE(0, 0);
    __syncthreads();
    int cur = 0;
    for (int c = 0; c < nch; ++c) {
        if (c + 1 < nch) STAGE(c + 1, cur ^ 1);
#pragma unroll
        for (int kk = 0; kk < 2; ++kk) {
            short8 af[8];
#pragma unroll
            for (int m = 0; m < 8; ++m) {
                int o = m * 16 + l15;
                int slot = (lg + 4 * kk) ^ (o & 7);
                af[m] = *(const short8*)&lA[cur][o * 64 + slot * 8];
            }
#pragma unroll
            for (int nf = 0; nf < 2; ++nf) {
                int pb = 32 * c + 16 * kk + 4 * lg;
                short8 bf;
#pragma unroll
                for (int j = 0; j < 4; ++j) {
                    int p = pb + j;
                    int row = s + p + ((p >= w) ? (FF - w) : 0);
                    float2 v = *(const float2*)(colbase + (size_t)row * 1024 + nf * 32);
                    bf[2 * j]     = (short)f2bf(v.x);
                    bf[2 * j + 1] = (short)f2bf(v.y);
                }
#pragma unroll
                for (int m = 0; m < 8; ++m)
                    acc[m][nf] = __builtin_amdgcn_mfma_f32_16x16x32_bf16(af[m], bf, acc[m][nf], 0, 0, 0);
            }
        }
        __syncthreads();
        cur ^= 1;
    }
#undef STAGE

    const float mu = musr[(b * NBANDS + band) * 2 + 0];
    const float rs = musr[(b * NBANDS + band) * 2 + 1];
#pragma unroll
    for (int m = 0; m < 8; ++m) {
#pragma unroll
        for (int r = 0; r < 4; ++r) {
            int o = m * 16 + lg * 4 + r;
            float wg = wgam[band * OUTC + o];
            float cb = wcb[band * OUTC + o];
            size_t rowoff = (((size_t)b * OUTC + o) * NBANDS + band) * TTS;
#pragma unroll
            for (int nf = 0; nf < 2; ++nf) {
                int t = tt0 + wv * 32 + nf * 16 + l15;
                out[rowoff + t] = rs * (acc[m][nf][r] - mu * wg) + cb;
            }
        }
    }
}

extern "C" void kernel_launch(void* const* d_in, const int* in_sizes, int n_in,
                              void* d_out, int out_size, void* d_ws, size_t ws_size,
                              hipStream_t stream) {
    const float* x     = (const float*)d_in[0];
    const float* gamma = (const float*)d_in[1];
    const float* beta  = (const float*)d_in[2];
    const float* W     = (const float*)d_in[3];
    const float* bias  = (const float*)d_in[4];
    float* out = (float*)d_out;
    float* ws  = (float*)d_ws;

    float* st_part = ws;            // 496 floats
    float* musr    = ws + 512;      // 496 floats
    float* wgam    = ws + 1024;     // 3968 floats
    float* wcb     = ws + 5120;     // 3968 floats
    unsigned short* wgP = (unsigned short*)(ws + 9216);  // 1220608 bf16 = 2.33 MB

    hipMemsetAsync(st_part, 0, (BB * NBANDS * 2) * sizeof(float), stream);
    stats_partial<<<dim3(79, BB * 2), 256, 0, stream>>>(x, st_part);
    finalize_stats<<<1, 256, 0, stream>>>(st_part, musr);
    wprep<<<dim3(NBANDS, OUTC / 16), 256, 0, stream>>>(W, gamma, beta, bias, wgam, wcb);
    wprep2<<<dim3(NBANDS, 32), 256, 0, stream>>>(W, gamma, wgP);
    gemm_mfma<<<dim3(16, NBANDS), 512, 0, stream>>>(x, wgP, musr, wgam, wcb, out);
}

// Round 4
// 132.093 us; speedup vs baseline: 5.3275x; 1.0283x over previous
//
#include <hip/hip_runtime.h>
#include <hip/hip_bf16.h>

typedef __attribute__((ext_vector_type(8))) short short8;
typedef __attribute__((ext_vector_type(4))) float f32x4;

#define NBANDS 31
#define BB 8
#define CCH 2
#define FF 2049
#define TTS 512
#define OUTC 128
#define TCH 8196
#define EPSV 1e-5f

__constant__ int c_wid[NBANDS] = {
    25,25,25,25,25,25,25,25,25,25,
    50,50,50,50,50,50,50,50,50,50,50,50,
    100,100,100,100,100,100,100,100,
    399};
__constant__ int c_start[NBANDS] = {
    0,25,50,75,100,125,150,175,200,225,
    250,300,350,400,450,500,550,600,650,700,750,800,
    850,950,1050,1150,1250,1350,1450,1550,
    1650};
__constant__ int c_cumf[NBANDS + 1] = {
    0,1,2,3,4,5,6,7,8,9,
    10,12,14,16,18,20,22,24,26,28,30,32,
    34,38,42,46,50,54,58,62,
    66,79};
// K padded to multiple of 64
__constant__ int c_kpad[NBANDS] = {
    128,128,128,128,128,128,128,128,128,128,
    256,256,256,256,256,256,256,256,256,256,256,256,
    448,448,448,448,448,448,448,448,
    1600};
// element base of each band's packed (swizzled, chunk-major) Wgamma panel
__constant__ int c_kbase[NBANDS] = {
    0,16384,32768,49152,65536,81920,98304,114688,131072,147456,
    163840,196608,229376,262144,294912,327680,360448,393216,425984,458752,491520,524288,
    557056,614400,671744,729088,786432,843776,901120,958464,
    1015808};
// heavy-first dispatch order (descending K)
__constant__ int c_order[NBANDS] = {
    30,22,23,24,25,26,27,28,29,
    10,11,12,13,14,15,16,17,18,19,20,21,
    0,1,2,3,4,5,6,7,8,9};

__device__ inline unsigned short f2bf(float f) {
    __hip_bfloat16 h = __float2bfloat16(f);
    unsigned short u;
    __builtin_memcpy(&u, &h, 2);
    return u;
}

__device__ inline void gload_lds16(const void* g, void* l) {
    __builtin_amdgcn_global_load_lds((const __attribute__((address_space(1))) void*)g,
                                     (__attribute__((address_space(3))) void*)l, 16, 0, 0);
}

// ---------------- stats: partial sums per (chunk, b, cc) -- no atomics, no memset ----------------
__global__ __launch_bounds__(256) void stats_partial(const float* __restrict__ x,
                                                     float* __restrict__ st) {
    int bx = blockIdx.x;                 // chunk id in [0,79)
    int band = 0;
    while (band + 1 < NBANDS && bx >= c_cumf[band + 1]) band++;
    int fc = bx - c_cumf[band];
    int b  = blockIdx.y >> 1;
    int cc = blockIdx.y & 1;
    int w = c_wid[band], s = c_start[band];
    int f0 = fc * 32;
    int rows = min(32, w - f0);

    const float4* p = (const float4*)(x + ((size_t)(b * CCH + cc) * FF + (s + f0)) * (TTS * 2));
    int n4 = rows * 256;
    float sum = 0.f, sq = 0.f;
    for (int i = threadIdx.x; i < n4; i += 256) {
        float4 v = p[i];
        sum += v.x + v.y + v.z + v.w;
        sq  += v.x * v.x + v.y * v.y + v.z * v.z + v.w * v.w;
    }
    __shared__ float s1[256], s2[256];
    int tid = threadIdx.x;
    s1[tid] = sum; s2[tid] = sq;
    __syncthreads();
    for (int st_ = 128; st_ > 0; st_ >>= 1) {
        if (tid < st_) { s1[tid] += s1[tid + st_]; s2[tid] += s2[tid + st_]; }
        __syncthreads();
    }
    if (tid == 0) {
        float* dst = st + (size_t)(bx * 16 + blockIdx.y) * 2;
        dst[0] = s1[0];
        dst[1] = s2[0];
    }
}

// gather partials: musr[(b,band)] = {mu, rsqrt(var+eps)}
__global__ void finalize_stats(const float* __restrict__ st, float* __restrict__ musr) {
    int i = blockIdx.x * blockDim.x + threadIdx.x;
    if (i < BB * NBANDS) {
        int b = i / NBANDS;
        int band = i - b * NBANDS;
        int c0 = c_cumf[band], c1 = c_cumf[band + 1];
        float sum = 0.f, sq = 0.f;
        for (int c = c0; c < c1; ++c) {
            for (int cc = 0; cc < 2; ++cc) {
                const float* p = st + (size_t)(c * 16 + b * 2 + cc) * 2;
                sum += p[0];
                sq  += p[1];
            }
        }
        float N = 4.f * (float)c_wid[band] * (float)TTS;
        float mu = sum / N;
        float var = sq / N - mu * mu;
        musr[2 * i]     = mu;
        musr[2 * i + 1] = rsqrtf(var + EPSV);
    }
}

// --------- wgam[band,o]=sum W*gamma ; wcb[band,o]=sum W*beta + bias ---------
__global__ __launch_bounds__(256) void wprep(const float* __restrict__ W,
                                             const float* __restrict__ gamma,
                                             const float* __restrict__ beta,
                                             const float* __restrict__ bias,
                                             float* __restrict__ wgam,
                                             float* __restrict__ wcb) {
    int band = blockIdx.x;
    int off = 4 * c_start[band];
    int ch  = 4 * c_wid[band];
    int o = blockIdx.y * 16 + (threadIdx.x >> 4);
    int lane = threadIdx.x & 15;
    const float* wrow = W + (size_t)o * TCH + off;
    float sg = 0.f, sb = 0.f;
    for (int c = lane; c < ch; c += 16) {
        float wv = wrow[c];
        sg += wv * gamma[off + c];
        sb += wv * beta[off + c];
    }
    for (int m = 8; m; m >>= 1) {
        sg += __shfl_down(sg, m, 16);
        sb += __shfl_down(sb, m, 16);
    }
    if (lane == 0) {
        wgam[band * OUTC + o] = sg;
        wcb[band * OUTC + o]  = sb + bias[band * OUTC + o];
    }
}

// --------- pack W*gamma into bf16 panels: chunk-major [c][o][64], slot-XOR swizzled,
// K permuted so k = 2*(cc*w+f)+ri ---------
__global__ __launch_bounds__(256) void wprep2(const float* __restrict__ W,
                                              const float* __restrict__ gamma,
                                              unsigned short* __restrict__ wgP) {
    int band = blockIdx.x;
    int w = c_wid[band];
    int s4 = 4 * c_start[band];
    int Kpad = c_kpad[band];
    int base = c_kbase[band];
    int K4 = 4 * w;
    int N = OUTC * Kpad;
    for (int idx = blockIdx.y * blockDim.x + threadIdx.x; idx < N;
         idx += gridDim.y * blockDim.x) {
        int o = idx / Kpad;
        int k = idx - o * Kpad;
        float val = 0.f;
        if (k < K4) {
            int ri = k & 1, p = k >> 1;
            int cc = (p >= w) ? 1 : 0;
            int f = p - cc * w;
            int c = s4 + ri * 2 * w + cc * w + f;
            val = W[(size_t)o * TCH + c] * gamma[c];
        }
        int slot = (k >> 3) & 7;
        int pos = (k >> 6) * 8192 + o * 64 + ((slot ^ (o & 7)) * 8) + (k & 7);
        wgP[base + pos] = f2bf(val);
    }
}

// ---------------- MFMA GEMM: Y[o,t] = Wg[o,:]*h[:,t], norm fused in epilogue ----------------
// grid (16 = 8b x 2 ttile, 31 bands), 512 threads = 8 waves, each wave: M=128 x N=32
__global__ __launch_bounds__(512) void gemm_mfma(const float* __restrict__ x,
                                                 const unsigned short* __restrict__ wgP,
                                                 const float* __restrict__ musr,
                                                 const float* __restrict__ wgam,
                                                 const float* __restrict__ wcb,
                                                 float* __restrict__ out) {
    const int band = c_order[blockIdx.y];
    const int b    = blockIdx.x >> 1;
    const int tt0  = (blockIdx.x & 1) * 256;
    const int w    = c_wid[band];
    const int s    = c_start[band];
    const int Kpad = c_kpad[band];
    const int nch  = Kpad >> 6;
    const unsigned short* wgA = wgP + c_kbase[band];

    __shared__ unsigned short lA[2][8192];   // 2 x 16KB: [o=128][k=64], slot-swizzled

    const int tid  = threadIdx.x;
    const int lane = tid & 63;
    const int wv   = tid >> 6;          // wave id -> t-block of 32
    const int l15  = lane & 15;
    const int lg   = lane >> 4;         // 0..3

    const float* xb = x + (size_t)b * (CCH * FF * TTS * 2);
    // per-lane t column (float index) for B loads: t = tt0 + wv*32 + nf*16 + l15
    const float* colbase = xb + (size_t)(tt0 + wv * 32 + l15) * 2;

    f32x4 acc[8][2] = {};

    // stage chunk c into buffer buf (16KB via global_load_lds dwordx4, 2 per thread)
#define STAGE(c, buf) do {                                                     \
    const unsigned short* srcc = wgA + (size_t)(c) * 8192;                     \
    gload_lds16(srcc + tid * 8,        &lA[buf][tid * 8]);                     \
    gload_lds16(srcc + 4096 + tid * 8, &lA[buf][4096 + tid * 8]);              \
} while (0)

    STAGE(0, 0);
    __syncthreads();
    int cur = 0;
    for (int c = 0; c < nch; ++c) {
        if (c + 1 < nch) STAGE(c + 1, cur ^ 1);
#pragma unroll
        for (int kk = 0; kk < 2; ++kk) {
            short8 af[8];
#pragma unroll
            for (int m = 0; m < 8; ++m) {
                int o = m * 16 + l15;
                int slot = (lg + 4 * kk) ^ (o & 7);
                af[m] = *(const short8*)&lA[cur][o * 64 + slot * 8];
            }
#pragma unroll
            for (int nf = 0; nf < 2; ++nf) {
                int pb = 32 * c + 16 * kk + 4 * lg;
                short8 bf;
#pragma unroll
                for (int j = 0; j < 4; ++j) {
                    int p = pb + j;
                    int row = s + p + ((p >= w) ? (FF - w) : 0);
                    float2 v = *(const float2*)(colbase + (size_t)row * 1024 + nf * 32);
                    bf[2 * j]     = (short)f2bf(v.x);
                    bf[2 * j + 1] = (short)f2bf(v.y);
                }
#pragma unroll
                for (int m = 0; m < 8; ++m)
                    acc[m][nf] = __builtin_amdgcn_mfma_f32_16x16x32_bf16(af[m], bf, acc[m][nf], 0, 0, 0);
            }
        }
        __syncthreads();
        cur ^= 1;
    }
#undef STAGE

    const float mu = musr[(b * NBANDS + band) * 2 + 0];
    const float rs = musr[(b * NBANDS + band) * 2 + 1];
#pragma unroll
    for (int m = 0; m < 8; ++m) {
#pragma unroll
        for (int r = 0; r < 4; ++r) {
            int o = m * 16 + lg * 4 + r;
            float wg = wgam[band * OUTC + o];
            float cb = wcb[band * OUTC + o];
            size_t rowoff = (((size_t)b * OUTC + o) * NBANDS + band) * TTS;
#pragma unroll
            for (int nf = 0; nf < 2; ++nf) {
                int t = tt0 + wv * 32 + nf * 16 + l15;
                out[rowoff + t] = rs * (acc[m][nf][r] - mu * wg) + cb;
            }
        }
    }
}

extern "C" void kernel_launch(void* const* d_in, const int* in_sizes, int n_in,
                              void* d_out, int out_size, void* d_ws, size_t ws_size,
                              hipStream_t stream) {
    const float* x     = (const float*)d_in[0];
    const float* gamma = (const float*)d_in[1];
    const float* beta  = (const float*)d_in[2];
    const float* W     = (const float*)d_in[3];
    const float* bias  = (const float*)d_in[4];
    float* out = (float*)d_out;
    float* ws  = (float*)d_ws;

    float* st_part = ws;            // 79*16*2 = 2528 floats (fully rewritten every call)
    float* musr    = ws + 2560;     // 496 floats
    float* wgam    = ws + 3072;     // 3968 floats
    float* wcb     = ws + 7168;     // 3968 floats
    unsigned short* wgP = (unsigned short*)(ws + 11264);  // 1220608 bf16 = 2.33 MB

    stats_partial<<<dim3(79, BB * 2), 256, 0, stream>>>(x, st_part);
    finalize_stats<<<1, 256, 0, stream>>>(st_part, musr);
    wprep<<<dim3(NBANDS, OUTC / 16), 256, 0, stream>>>(W, gamma, beta, bias, wgam, wcb);
    wprep2<<<dim3(NBANDS, 32), 256, 0, stream>>>(W, gamma, wgP);
    gemm_mfma<<<dim3(16, NBANDS), 512, 0, stream>>>(x, wgP, musr, wgam, wcb, out);
}

// Round 5
// 130.047 us; speedup vs baseline: 5.4112x; 1.0157x over previous
//
#include <hip/hip_runtime.h>
#include <hip/hip_bf16.h>

typedef __attribute__((ext_vector_type(8))) short short8;
typedef __attribute__((ext_vector_type(4))) float f32x4;

#define NBANDS 31
#define BB 8
#define CCH 2
#define FF 2049
#define TTS 512
#define OUTC 128
#define TCH 8196
#define EPSV 1e-5f

__constant__ int c_wid[NBANDS] = {
    25,25,25,25,25,25,25,25,25,25,
    50,50,50,50,50,50,50,50,50,50,50,50,
    100,100,100,100,100,100,100,100,
    399};
__constant__ int c_start[NBANDS] = {
    0,25,50,75,100,125,150,175,200,225,
    250,300,350,400,450,500,550,600,650,700,750,800,
    850,950,1050,1150,1250,1350,1450,1550,
    1650};
__constant__ int c_cumf[NBANDS + 1] = {
    0,1,2,3,4,5,6,7,8,9,
    10,12,14,16,18,20,22,24,26,28,30,32,
    34,38,42,46,50,54,58,62,
    66,79};
// K padded to multiple of 64
__constant__ int c_kpad[NBANDS] = {
    128,128,128,128,128,128,128,128,128,128,
    256,256,256,256,256,256,256,256,256,256,256,256,
    448,448,448,448,448,448,448,448,
    1600};
// element base of each band's packed (swizzled, chunk-major) Wgamma panel
__constant__ int c_kbase[NBANDS] = {
    0,16384,32768,49152,65536,81920,98304,114688,131072,147456,
    163840,196608,229376,262144,294912,327680,360448,393216,425984,458752,491520,524288,
    557056,614400,671744,729088,786432,843776,901120,958464,
    1015808};
// heavy-first dispatch order (descending K)
__constant__ int c_order[NBANDS] = {
    30,22,23,24,25,26,27,28,29,
    10,11,12,13,14,15,16,17,18,19,20,21,
    0,1,2,3,4,5,6,7,8,9};

__device__ inline unsigned short f2bf(float f) {
    __hip_bfloat16 h = __float2bfloat16(f);
    unsigned short u;
    __builtin_memcpy(&u, &h, 2);
    return u;
}

__device__ inline void gload_lds16(const void* g, void* l) {
    __builtin_amdgcn_global_load_lds((const __attribute__((address_space(1))) void*)g,
                                     (__attribute__((address_space(3))) void*)l, 16, 0, 0);
}

// ---------------- stats: partial sums per (chunk, b, cc) -- no atomics, no memset ----------------
__global__ __launch_bounds__(256) void stats_partial(const float* __restrict__ x,
                                                     float* __restrict__ st) {
    int bx = blockIdx.x;                 // chunk id in [0,79)
    int band = 0;
    while (band + 1 < NBANDS && bx >= c_cumf[band + 1]) band++;
    int fc = bx - c_cumf[band];
    int b  = blockIdx.y >> 1;
    int cc = blockIdx.y & 1;
    int w = c_wid[band], s = c_start[band];
    int f0 = fc * 32;
    int rows = min(32, w - f0);

    const float4* p = (const float4*)(x + ((size_t)(b * CCH + cc) * FF + (s + f0)) * (TTS * 2));
    int n4 = rows * 256;
    float sum = 0.f, sq = 0.f;
    for (int i = threadIdx.x; i < n4; i += 256) {
        float4 v = p[i];
        sum += v.x + v.y + v.z + v.w;
        sq  += v.x * v.x + v.y * v.y + v.z * v.z + v.w * v.w;
    }
    __shared__ float s1[256], s2[256];
    int tid = threadIdx.x;
    s1[tid] = sum; s2[tid] = sq;
    __syncthreads();
    for (int st_ = 128; st_ > 0; st_ >>= 1) {
        if (tid < st_) { s1[tid] += s1[tid + st_]; s2[tid] += s2[tid + st_]; }
        __syncthreads();
    }
    if (tid == 0) {
        float* dst = st + (size_t)(bx * 16 + blockIdx.y) * 2;
        dst[0] = s1[0];
        dst[1] = s2[0];
    }
}

// gather partials: musr[(b,band)] = {mu, rsqrt(var+eps)}
__global__ void finalize_stats(const float* __restrict__ st, float* __restrict__ musr) {
    int i = blockIdx.x * blockDim.x + threadIdx.x;
    if (i < BB * NBANDS) {
        int b = i / NBANDS;
        int band = i - b * NBANDS;
        int c0 = c_cumf[band], c1 = c_cumf[band + 1];
        float sum = 0.f, sq = 0.f;
        for (int c = c0; c < c1; ++c) {
            for (int cc = 0; cc < 2; ++cc) {
                const float* p = st + (size_t)(c * 16 + b * 2 + cc) * 2;
                sum += p[0];
                sq  += p[1];
            }
        }
        float N = 4.f * (float)c_wid[band] * (float)TTS;
        float mu = sum / N;
        float var = sq / N - mu * mu;
        musr[2 * i]     = mu;
        musr[2 * i + 1] = rsqrtf(var + EPSV);
    }
}

// --------- wgam[band,o]=sum W*gamma ; wcb[band,o]=sum W*beta + bias ---------
__global__ __launch_bounds__(256) void wprep(const float* __restrict__ W,
                                             const float* __restrict__ gamma,
                                             const float* __restrict__ beta,
                                             const float* __restrict__ bias,
                                             float* __restrict__ wgam,
                                             float* __restrict__ wcb) {
    int band = blockIdx.x;
    int off = 4 * c_start[band];
    int ch  = 4 * c_wid[band];
    int o = blockIdx.y * 16 + (threadIdx.x >> 4);
    int lane = threadIdx.x & 15;
    const float* wrow = W + (size_t)o * TCH + off;
    float sg = 0.f, sb = 0.f;
    for (int c = lane; c < ch; c += 16) {
        float wv = wrow[c];
        sg += wv * gamma[off + c];
        sb += wv * beta[off + c];
    }
    for (int m = 8; m; m >>= 1) {
        sg += __shfl_down(sg, m, 16);
        sb += __shfl_down(sb, m, 16);
    }
    if (lane == 0) {
        wgam[band * OUTC + o] = sg;
        wcb[band * OUTC + o]  = sb + bias[band * OUTC + o];
    }
}

// --------- pack W*gamma into bf16 panels: chunk-major [c][o][64], slot-XOR swizzled,
// K permuted so k = 2*(cc*w+f)+ri ---------
__global__ __launch_bounds__(256) void wprep2(const float* __restrict__ W,
                                              const float* __restrict__ gamma,
                                              unsigned short* __restrict__ wgP) {
    int band = blockIdx.x;
    int w = c_wid[band];
    int s4 = 4 * c_start[band];
    int Kpad = c_kpad[band];
    int base = c_kbase[band];
    int K4 = 4 * w;
    int N = OUTC * Kpad;
    for (int idx = blockIdx.y * blockDim.x + threadIdx.x; idx < N;
         idx += gridDim.y * blockDim.x) {
        int o = idx / Kpad;
        int k = idx - o * Kpad;
        float val = 0.f;
        if (k < K4) {
            int ri = k & 1, p = k >> 1;
            int cc = (p >= w) ? 1 : 0;
            int f = p - cc * w;
            int c = s4 + ri * 2 * w + cc * w + f;
            val = W[(size_t)o * TCH + c] * gamma[c];
        }
        int slot = (k >> 3) & 7;
        int pos = (k >> 6) * 8192 + o * 64 + ((slot ^ (o & 7)) * 8) + (k & 7);
        wgP[base + pos] = f2bf(val);
    }
}

// ---------------- MFMA GEMM: Y[o,t] = Wg[o,:]*h[:,t], norm fused in epilogue ----------------
// grid (16 = 8b x 2 ttile, 31 bands), 512 threads = 8 waves, each wave: M=128 x N=32
// B tile register-prefetched one chunk ahead (ping-pong bA/bB), A via global_load_lds dbuf.
__global__ __launch_bounds__(512) void gemm_mfma(const float* __restrict__ x,
                                                 const unsigned short* __restrict__ wgP,
                                                 const float* __restrict__ musr,
                                                 const float* __restrict__ wgam,
                                                 const float* __restrict__ wcb,
                                                 float* __restrict__ out) {
    const int band = c_order[blockIdx.y];
    const int b    = blockIdx.x >> 1;
    const int tt0  = (blockIdx.x & 1) * 256;
    const int w    = c_wid[band];
    const int s    = c_start[band];
    const int w2   = 2 * w;
    const int Kpad = c_kpad[band];
    const int nch  = Kpad >> 6;
    const unsigned short* wgA = wgP + c_kbase[band];

    __shared__ unsigned short lA[2][8192];   // 2 x 16KB: [o=128][k=64], slot-swizzled

    const int tid  = threadIdx.x;
    const int lane = tid & 63;
    const int wv   = tid >> 6;          // wave id -> t-block of 32
    const int l15  = lane & 15;
    const int lg   = lane >> 4;         // 0..3

    const float* xb = x + (size_t)b * (CCH * FF * TTS * 2);
    // per-lane t column (float index) for B loads: t = tt0 + wv*32 + nf*16 + l15
    const float* colbase = xb + (size_t)(tt0 + wv * 32 + l15) * 2;

    f32x4 acc[8][2] = {};
    float2 bA[16], bB[16];

    // issue 16 float2 loads of chunk c's B tile into dst (row clamped: A-zeros kill junk)
#define LOADB(c, dst) do {                                                     \
    _Pragma("unroll")                                                          \
    for (int kk = 0; kk < 2; ++kk)                                             \
        _Pragma("unroll")                                                      \
        for (int nf = 0; nf < 2; ++nf)                                         \
            _Pragma("unroll")                                                  \
            for (int j = 0; j < 4; ++j) {                                      \
                int p = 32 * (c) + 16 * kk + 4 * lg + j;                       \
                p = min(p, w2 - 1);                                            \
                int row = s + p + ((p >= w) ? (FF - w) : 0);                   \
                dst[kk * 8 + nf * 4 + j] =                                     \
                    *(const float2*)(colbase + (size_t)row * 1024 + nf * 32);  \
            }                                                                  \
} while (0)

    // stage chunk c's A panel into LDS buffer buf (16KB via global_load_lds dwordx4)
#define STAGE(c, buf) do {                                                     \
    const unsigned short* srcc = wgA + (size_t)(c) * 8192;                     \
    gload_lds16(srcc + tid * 8,        &lA[buf][tid * 8]);                     \
    gload_lds16(srcc + 4096 + tid * 8, &lA[buf][4096 + tid * 8]);              \
} while (0)

    // cvt + 32 MFMA on chunk whose B regs are in br and A panel in lA[buf]
#define COMPUTE(br, buf) do {                                                  \
    _Pragma("unroll")                                                          \
    for (int kk = 0; kk < 2; ++kk) {                                           \
        short8 af[8];                                                          \
        _Pragma("unroll")                                                      \
        for (int m = 0; m < 8; ++m) {                                          \
            int o = m * 16 + l15;                                              \
            int slot = (lg + 4 * kk) ^ (o & 7);                                \
            af[m] = *(const short8*)&lA[buf][o * 64 + slot * 8];               \
        }                                                                      \
        _Pragma("unroll")                                                      \
        for (int nf = 0; nf < 2; ++nf) {                                       \
            short8 bf;                                                         \
            _Pragma("unroll")                                                  \
            for (int j = 0; j < 4; ++j) {                                      \
                float2 v = br[kk * 8 + nf * 4 + j];                            \
                bf[2 * j]     = (short)f2bf(v.x);                              \
                bf[2 * j + 1] = (short)f2bf(v.y);                              \
            }                                                                  \
            _Pragma("unroll")                                                  \
            for (int m = 0; m < 8; ++m)                                        \
                acc[m][nf] = __builtin_amdgcn_mfma_f32_16x16x32_bf16(          \
                    af[m], bf, acc[m][nf], 0, 0, 0);                           \
        }                                                                      \
    }                                                                          \
} while (0)

    LOADB(0, bA);
    STAGE(0, 0);
    __syncthreads();
    for (int c = 0; c < nch; c += 2) {
        if (c + 1 < nch) { LOADB(c + 1, bB); STAGE(c + 1, 1); }
        COMPUTE(bA, 0);
        __syncthreads();
        if (c + 1 < nch) {
            if (c + 2 < nch) { LOADB(c + 2, bA); STAGE(c + 2, 0); }
            COMPUTE(bB, 1);
            __syncthreads();
        }
    }
#undef LOADB
#undef STAGE
#undef COMPUTE

    const float mu = musr[(b * NBANDS + band) * 2 + 0];
    const float rs = musr[(b * NBANDS + band) * 2 + 1];
#pragma unroll
    for (int m = 0; m < 8; ++m) {
#pragma unroll
        for (int r = 0; r < 4; ++r) {
            int o = m * 16 + lg * 4 + r;
            float wg = wgam[band * OUTC + o];
            float cb = wcb[band * OUTC + o];
            size_t rowoff = (((size_t)b * OUTC + o) * NBANDS + band) * TTS;
#pragma unroll
            for (int nf = 0; nf < 2; ++nf) {
                int t = tt0 + wv * 32 + nf * 16 + l15;
                out[rowoff + t] = rs * (acc[m][nf][r] - mu * wg) + cb;
            }
        }
    }
}

extern "C" void kernel_launch(void* const* d_in, const int* in_sizes, int n_in,
                              void* d_out, int out_size, void* d_ws, size_t ws_size,
                              hipStream_t stream) {
    const float* x     = (const float*)d_in[0];
    const float* gamma = (const float*)d_in[1];
    const float* beta  = (const float*)d_in[2];
    const float* W     = (const float*)d_in[3];
    const float* bias  = (const float*)d_in[4];
    float* out = (float*)d_out;
    float* ws  = (float*)d_ws;

    float* st_part = ws;            // 79*16*2 = 2528 floats (fully rewritten every call)
    float* musr    = ws + 2560;     // 496 floats
    float* wgam    = ws + 3072;     // 3968 floats
    float* wcb     = ws + 7168;     // 3968 floats
    unsigned short* wgP = (unsigned short*)(ws + 11264);  // 1220608 bf16 = 2.33 MB

    stats_partial<<<dim3(79, BB * 2), 256, 0, stream>>>(x, st_part);
    finalize_stats<<<1, 256, 0, stream>>>(st_part, musr);
    wprep<<<dim3(NBANDS, OUTC / 16), 256, 0, stream>>>(W, gamma, beta, bias, wgam, wcb);
    wprep2<<<dim3(NBANDS, 32), 256, 0, stream>>>(W, gamma, wgP);
    gemm_mfma<<<dim3(16, NBANDS), 512, 0, stream>>>(x, wgP, musr, wgam, wcb, out);
}

// Round 6
// 127.367 us; speedup vs baseline: 5.5251x; 1.0210x over previous
//
#include <hip/hip_runtime.h>
#include <hip/hip_bf16.h>

typedef __attribute__((ext_vector_type(8))) short short8;
typedef __attribute__((ext_vector_type(4))) float f32x4;

#define NBANDS 31
#define BB 8
#define CCH 2
#define FF 2049
#define TTS 512
#define OUTC 128
#define TCH 8196
#define EPSV 1e-5f

__constant__ int c_wid[NBANDS] = {
    25,25,25,25,25,25,25,25,25,25,
    50,50,50,50,50,50,50,50,50,50,50,50,
    100,100,100,100,100,100,100,100,
    399};
__constant__ int c_start[NBANDS] = {
    0,25,50,75,100,125,150,175,200,225,
    250,300,350,400,450,500,550,600,650,700,750,800,
    850,950,1050,1150,1250,1350,1450,1550,
    1650};
__constant__ int c_cumf[NBANDS + 1] = {
    0,1,2,3,4,5,6,7,8,9,
    10,12,14,16,18,20,22,24,26,28,30,32,
    34,38,42,46,50,54,58,62,
    66,79};
// K padded to multiple of 64
__constant__ int c_kpad[NBANDS] = {
    128,128,128,128,128,128,128,128,128,128,
    256,256,256,256,256,256,256,256,256,256,256,256,
    448,448,448,448,448,448,448,448,
    1600};
// element base of each band's packed (swizzled, chunk-major) Wgamma panel
__constant__ int c_kbase[NBANDS] = {
    0,16384,32768,49152,65536,81920,98304,114688,131072,147456,
    163840,196608,229376,262144,294912,327680,360448,393216,425984,458752,491520,524288,
    557056,614400,671744,729088,786432,843776,901120,958464,
    1015808};
// heavy-first dispatch order (descending K)
__constant__ int c_order[NBANDS] = {
    30,22,23,24,25,26,27,28,29,
    10,11,12,13,14,15,16,17,18,19,20,21,
    0,1,2,3,4,5,6,7,8,9};

__device__ inline unsigned short f2bf(float f) {
    __hip_bfloat16 h = __float2bfloat16(f);
    unsigned short u;
    __builtin_memcpy(&u, &h, 2);
    return u;
}

__device__ inline void gload_lds16(const void* g, void* l) {
    __builtin_amdgcn_global_load_lds((const __attribute__((address_space(1))) void*)g,
                                     (__attribute__((address_space(3))) void*)l, 16, 0, 0);
}

// ---------------- stats: partial sums per (chunk, b, cc) -- no atomics, no memset ----------------
__global__ __launch_bounds__(256) void stats_partial(const float* __restrict__ x,
                                                     float* __restrict__ st) {
    int bx = blockIdx.x;                 // chunk id in [0,79)
    int band = 0;
    while (band + 1 < NBANDS && bx >= c_cumf[band + 1]) band++;
    int fc = bx - c_cumf[band];
    int b  = blockIdx.y >> 1;
    int cc = blockIdx.y & 1;
    int w = c_wid[band], s = c_start[band];
    int f0 = fc * 32;
    int rows = min(32, w - f0);

    const float4* p = (const float4*)(x + ((size_t)(b * CCH + cc) * FF + (s + f0)) * (TTS * 2));
    int n4 = rows * 256;
    float sum = 0.f, sq = 0.f;
    for (int i = threadIdx.x; i < n4; i += 256) {
        float4 v = p[i];
        sum += v.x + v.y + v.z + v.w;
        sq  += v.x * v.x + v.y * v.y + v.z * v.z + v.w * v.w;
    }
    __shared__ float s1[256], s2[256];
    int tid = threadIdx.x;
    s1[tid] = sum; s2[tid] = sq;
    __syncthreads();
    for (int st_ = 128; st_ > 0; st_ >>= 1) {
        if (tid < st_) { s1[tid] += s1[tid + st_]; s2[tid] += s2[tid + st_]; }
        __syncthreads();
    }
    if (tid == 0) {
        float* dst = st + (size_t)(bx * 16 + blockIdx.y) * 2;
        dst[0] = s1[0];
        dst[1] = s2[0];
    }
}

// gather partials: musr[(b,band)] = {mu, rsqrt(var+eps)}
__global__ void finalize_stats(const float* __restrict__ st, float* __restrict__ musr) {
    int i = blockIdx.x * blockDim.x + threadIdx.x;
    if (i < BB * NBANDS) {
        int b = i / NBANDS;
        int band = i - b * NBANDS;
        int c0 = c_cumf[band], c1 = c_cumf[band + 1];
        float sum = 0.f, sq = 0.f;
        for (int c = c0; c < c1; ++c) {
            for (int cc = 0; cc < 2; ++cc) {
                const float* p = st + (size_t)(c * 16 + b * 2 + cc) * 2;
                sum += p[0];
                sq  += p[1];
            }
        }
        float N = 4.f * (float)c_wid[band] * (float)TTS;
        float mu = sum / N;
        float var = sq / N - mu * mu;
        musr[2 * i]     = mu;
        musr[2 * i + 1] = rsqrtf(var + EPSV);
    }
}

// --------- wgam[band,o]=sum W*gamma ; wcb[band,o]=sum W*beta + bias ---------
__global__ __launch_bounds__(256) void wprep(const float* __restrict__ W,
                                             const float* __restrict__ gamma,
                                             const float* __restrict__ beta,
                                             const float* __restrict__ bias,
                                             float* __restrict__ wgam,
                                             float* __restrict__ wcb) {
    int band = blockIdx.x;
    int off = 4 * c_start[band];
    int ch  = 4 * c_wid[band];
    int o = blockIdx.y * 16 + (threadIdx.x >> 4);
    int lane = threadIdx.x & 15;
    const float* wrow = W + (size_t)o * TCH + off;
    float sg = 0.f, sb = 0.f;
    for (int c = lane; c < ch; c += 16) {
        float wv = wrow[c];
        sg += wv * gamma[off + c];
        sb += wv * beta[off + c];
    }
    for (int m = 8; m; m >>= 1) {
        sg += __shfl_down(sg, m, 16);
        sb += __shfl_down(sb, m, 16);
    }
    if (lane == 0) {
        wgam[band * OUTC + o] = sg;
        wcb[band * OUTC + o]  = sb + bias[band * OUTC + o];
    }
}

// --------- pack W*gamma into bf16 panels: chunk-major [c][o][64], slot-XOR swizzled,
// K permuted so k = 2*(cc*w+f)+ri ---------
__global__ __launch_bounds__(256) void wprep2(const float* __restrict__ W,
                                              const float* __restrict__ gamma,
                                              unsigned short* __restrict__ wgP) {
    int band = blockIdx.x;
    int w = c_wid[band];
    int s4 = 4 * c_start[band];
    int Kpad = c_kpad[band];
    int base = c_kbase[band];
    int K4 = 4 * w;
    int N = OUTC * Kpad;
    for (int idx = blockIdx.y * blockDim.x + threadIdx.x; idx < N;
         idx += gridDim.y * blockDim.x) {
        int o = idx / Kpad;
        int k = idx - o * Kpad;
        float val = 0.f;
        if (k < K4) {
            int ri = k & 1, p = k >> 1;
            int cc = (p >= w) ? 1 : 0;
            int f = p - cc * w;
            int c = s4 + ri * 2 * w + cc * w + f;
            val = W[(size_t)o * TCH + c] * gamma[c];
        }
        int slot = (k >> 3) & 7;
        int pos = (k >> 6) * 8192 + o * 64 + ((slot ^ (o & 7)) * 8) + (k & 7);
        wgP[base + pos] = f2bf(val);
    }
}

// ---------------- MFMA GEMM: Y[o,t] = Wg[o,:]*h[:,t], norm fused in epilogue ----------------
// grid (16 = 8b x 2 ttile, 31 bands), 512 threads = 8 waves, each wave: M=128 x N=32
// B tile register-prefetched one chunk ahead (ping-pong bA/bB), A via global_load_lds dbuf.
__global__ __launch_bounds__(512) void gemm_mfma(const float* __restrict__ x,
                                                 const unsigned short* __restrict__ wgP,
                                                 const float* __restrict__ musr,
                                                 const float* __restrict__ wgam,
                                                 const float* __restrict__ wcb,
                                                 float* __restrict__ out) {
    const int band = c_order[blockIdx.y];
    const int b    = blockIdx.x >> 1;
    const int tt0  = (blockIdx.x & 1) * 256;
    const int w    = c_wid[band];
    const int s    = c_start[band];
    const int w2   = 2 * w;
    const int Kpad = c_kpad[band];
    const int nch  = Kpad >> 6;
    const unsigned short* wgA = wgP + c_kbase[band];

    __shared__ unsigned short lA[2][8192];   // 2 x 16KB: [o=128][k=64], slot-swizzled

    const int tid  = threadIdx.x;
    const int lane = tid & 63;
    const int wv   = tid >> 6;          // wave id -> t-block of 32
    const int l15  = lane & 15;
    const int lg   = lane >> 4;         // 0..3

    const float* xb = x + (size_t)b * (CCH * FF * TTS * 2);
    // per-lane t column (float index) for B loads: t = tt0 + wv*32 + nf*16 + l15
    const float* colbase = xb + (size_t)(tt0 + wv * 32 + l15) * 2;

    f32x4 acc[8][2] = {};
    float2 bA[16], bB[16];

    // issue 16 float2 loads of chunk c's B tile into dst (row clamped: A-zeros kill junk)
#define LOADB(c, dst) do {                                                     \
    _Pragma("unroll")                                                          \
    for (int kk = 0; kk < 2; ++kk)                                             \
        _Pragma("unroll")                                                      \
        for (int nf = 0; nf < 2; ++nf)                                         \
            _Pragma("unroll")                                                  \
            for (int j = 0; j < 4; ++j) {                                      \
                int p = 32 * (c) + 16 * kk + 4 * lg + j;                       \
                p = min(p, w2 - 1);                                            \
                int row = s + p + ((p >= w) ? (FF - w) : 0);                   \
                dst[kk * 8 + nf * 4 + j] =                                     \
                    *(const float2*)(colbase + (size_t)row * 1024 + nf * 32);  \
            }                                                                  \
} while (0)

    // stage chunk c's A panel into LDS buffer buf (16KB via global_load_lds dwordx4)
#define STAGE(c, buf) do {                                                     \
    const unsigned short* srcc = wgA + (size_t)(c) * 8192;                     \
    gload_lds16(srcc + tid * 8,        &lA[buf][tid * 8]);                     \
    gload_lds16(srcc + 4096 + tid * 8, &lA[buf][4096 + tid * 8]);              \
} while (0)

    // cvt + 32 MFMA on chunk whose B regs are in br and A panel in lA[buf]
#define COMPUTE(br, buf) do {                                                  \
    _Pragma("unroll")                                                          \
    for (int kk = 0; kk < 2; ++kk) {                                           \
        short8 af[8];                                                          \
        _Pragma("unroll")                                                      \
        for (int m = 0; m < 8; ++m) {                                          \
            int o = m * 16 + l15;                                              \
            int slot = (lg + 4 * kk) ^ (o & 7);                                \
            af[m] = *(const short8*)&lA[buf][o * 64 + slot * 8];               \
        }                                                                      \
        _Pragma("unroll")                                                      \
        for (int nf = 0; nf < 2; ++nf) {                                       \
            short8 bf;                                                         \
            _Pragma("unroll")                                                  \
            for (int j = 0; j < 4; ++j) {                                      \
                float2 v = br[kk * 8 + nf * 4 + j];                            \
                bf[2 * j]     = (short)f2bf(v.x);                              \
                bf[2 * j + 1] = (short)f2bf(v.y);                              \
            }                                                                  \
            _Pragma("unroll")                                                  \
            for (int m = 0; m < 8; ++m)                                        \
                acc[m][nf] = __builtin_amdgcn_mfma_f32_16x16x32_bf16(          \
                    af[m], bf, acc[m][nf], 0, 0, 0);                           \
        }                                                                      \
    }                                                                          \
} while (0)

    LOADB(0, bA);
    STAGE(0, 0);
    __syncthreads();
    for (int c = 0; c < nch; c += 2) {
        if (c + 1 < nch) { LOADB(c + 1, bB); STAGE(c + 1, 1); }
        COMPUTE(bA, 0);
        __syncthreads();
        if (c + 1 < nch) {
            if (c + 2 < nch) { LOADB(c + 2, bA); STAGE(c + 2, 0); }
            COMPUTE(bB, 1);
            __syncthreads();
        }
    }
#undef LOADB
#undef STAGE
#undef COMPUTE

    const float mu = musr[(b * NBANDS + band) * 2 + 0];
    const float rs = musr[(b * NBANDS + band) * 2 + 1];
#pragma unroll
    for (int m = 0; m < 8; ++m) {
#pragma unroll
        for (int r = 0; r < 4; ++r) {
            int o = m * 16 + lg * 4 + r;
            float wg = wgam[band * OUTC + o];
            float cb = wcb[band * OUTC + o];
            size_t rowoff = (((size_t)b * OUTC + o) * NBANDS + band) * TTS;
#pragma unroll
            for (int nf = 0; nf < 2; ++nf) {
                int t = tt0 + wv * 32 + nf * 16 + l15;
                out[rowoff + t] = rs * (acc[m][nf][r] - mu * wg) + cb;
            }
        }
    }
}

extern "C" void kernel_launch(void* const* d_in, const int* in_sizes, int n_in,
                              void* d_out, int out_size, void* d_ws, size_t ws_size,
                              hipStream_t stream) {
    const float* x     = (const float*)d_in[0];
    const float* gamma = (const float*)d_in[1];
    const float* beta  = (const float*)d_in[2];
    const float* W     = (const float*)d_in[3];
    const float* bias  = (const float*)d_in[4];
    float* out = (float*)d_out;
    float* ws  = (float*)d_ws;

    float* st_part = ws;            // 79*16*2 = 2528 floats (fully rewritten every call)
    float* musr    = ws + 2560;     // 496 floats
    float* wgam    = ws + 3072;     // 3968 floats
    float* wcb     = ws + 7168;     // 3968 floats
    unsigned short* wgP = (unsigned short*)(ws + 11264);  // 1220608 bf16 = 2.33 MB

    stats_partial<<<dim3(79, BB * 2), 256, 0, stream>>>(x, st_part);
    finalize_stats<<<1, 256, 0, stream>>>(st_part, musr);
    wprep<<<dim3(NBANDS, OUTC / 16), 256, 0, stream>>>(W, gamma, beta, bias, wgam, wcb);
    wprep2<<<dim3(NBANDS, 32), 256, 0, stream>>>(W, gamma, wgP);
    gemm_mfma<<<dim3(16, NBANDS), 512, 0, stream>>>(x, wgP, musr, wgam, wcb, out);
}

// Round 7
// 92.719 us; speedup vs baseline: 7.5898x; 1.3737x over previous
//
#include <hip/hip_runtime.h>
#include <hip/hip_bf16.h>

typedef __attribute__((ext_vector_type(8))) short short8;
typedef __attribute__((ext_vector_type(4))) float f32x4;

#define NBANDS 31
#define BB 8
#define CCH 2
#define FF 2049
#define TTS 512
#define OUTC 128
#define TCH 8196
#define EPSV 1e-5f

__constant__ int c_wid[NBANDS] = {
    25,25,25,25,25,25,25,25,25,25,
    50,50,50,50,50,50,50,50,50,50,50,50,
    100,100,100,100,100,100,100,100,
    399};
__constant__ int c_start[NBANDS] = {
    0,25,50,75,100,125,150,175,200,225,
    250,300,350,400,450,500,550,600,650,700,750,800,
    850,950,1050,1150,1250,1350,1450,1550,
    1650};
__constant__ int c_cumf[NBANDS + 1] = {
    0,1,2,3,4,5,6,7,8,9,
    10,12,14,16,18,20,22,24,26,28,30,32,
    34,38,42,46,50,54,58,62,
    66,79};
// K padded to multiple of 64
__constant__ int c_kpad[NBANDS] = {
    128,128,128,128,128,128,128,128,128,128,
    256,256,256,256,256,256,256,256,256,256,256,256,
    448,448,448,448,448,448,448,448,
    1600};
// element base of each band's packed (swizzled, chunk-major) Wgamma panel
__constant__ int c_kbase[NBANDS] = {
    0,16384,32768,49152,65536,81920,98304,114688,131072,147456,
    163840,196608,229376,262144,294912,327680,360448,393216,425984,458752,491520,524288,
    557056,614400,671744,729088,786432,843776,901120,958464,
    1015808};
// heavy-first dispatch order (descending K)
__constant__ int c_order[NBANDS] = {
    30,22,23,24,25,26,27,28,29,
    10,11,12,13,14,15,16,17,18,19,20,21,
    0,1,2,3,4,5,6,7,8,9};

#define NSTATS 1264   // 79 chunks x 16 (b,cc)
#define NWPREP 248    // 31 bands x 8 o-groups
#define NWP2   992    // 31 bands x 32

__device__ inline unsigned short f2bf(float f) {
    __hip_bfloat16 h = __float2bfloat16(f);
    unsigned short u;
    __builtin_memcpy(&u, &h, 2);
    return u;
}

__device__ inline void gload_lds16(const void* g, void* l) {
    __builtin_amdgcn_global_load_lds((const __attribute__((address_space(1))) void*)g,
                                     (__attribute__((address_space(3))) void*)l, 16, 0, 0);
}

// ---------------- fused prep: stats partials | wgam/wcb | packed A panels ----------------
__global__ __launch_bounds__(256) void prep(const float* __restrict__ x,
                                            const float* __restrict__ W,
                                            const float* __restrict__ gamma,
                                            const float* __restrict__ beta,
                                            const float* __restrict__ bias,
                                            float* __restrict__ st,
                                            float* __restrict__ wgam,
                                            float* __restrict__ wcb,
                                            unsigned short* __restrict__ wgP) {
    __shared__ float s1[256], s2[256];
    const int bid = blockIdx.x;
    const int tid = threadIdx.x;

    if (bid < NSTATS) {
        // ---- stats role: partial sum/sumsq per (chunk, b, cc) ----
        int bx  = bid >> 4;              // chunk id [0,79)
        int ycc = bid & 15;              // (b<<1)|cc
        int band = 0;
        while (band + 1 < NBANDS && bx >= c_cumf[band + 1]) band++;
        int fc = bx - c_cumf[band];
        int b  = ycc >> 1;
        int cc = ycc & 1;
        int w = c_wid[band], s = c_start[band];
        int f0 = fc * 32;
        int rows = min(32, w - f0);

        const float4* p = (const float4*)(x + ((size_t)(b * CCH + cc) * FF + (s + f0)) * (TTS * 2));
        int n4 = rows * 256;
        float sum = 0.f, sq = 0.f;
        for (int i = tid; i < n4; i += 256) {
            float4 v = p[i];
            sum += v.x + v.y + v.z + v.w;
            sq  += v.x * v.x + v.y * v.y + v.z * v.z + v.w * v.w;
        }
        s1[tid] = sum; s2[tid] = sq;
        __syncthreads();
        for (int st_ = 128; st_ > 0; st_ >>= 1) {
            if (tid < st_) { s1[tid] += s1[tid + st_]; s2[tid] += s2[tid + st_]; }
            __syncthreads();
        }
        if (tid == 0) {
            float* dst = st + (size_t)(bx * 16 + ycc) * 2;
            dst[0] = s1[0];
            dst[1] = s2[0];
        }
    } else if (bid < NSTATS + NWPREP) {
        // ---- wprep role: wgam/wcb reductions ----
        int r = bid - NSTATS;
        int band = r >> 3;
        int off = 4 * c_start[band];
        int ch  = 4 * c_wid[band];
        int o = (r & 7) * 16 + (tid >> 4);
        int lane = tid & 15;
        const float* wrow = W + (size_t)o * TCH + off;
        float sg = 0.f, sb = 0.f;
        for (int c = lane; c < ch; c += 16) {
            float wv = wrow[c];
            sg += wv * gamma[off + c];
            sb += wv * beta[off + c];
        }
        for (int m = 8; m; m >>= 1) {
            sg += __shfl_down(sg, m, 16);
            sb += __shfl_down(sb, m, 16);
        }
        if (lane == 0) {
            wgam[band * OUTC + o] = sg;
            wcb[band * OUTC + o]  = sb + bias[band * OUTC + o];
        }
    } else {
        // ---- wprep2 role: pack W*gamma bf16 panels, chunk-major, slot-XOR swizzled ----
        int r = bid - (NSTATS + NWPREP);
        int band = r % NBANDS;
        int gy   = r / NBANDS;           // 0..31
        int w = c_wid[band];
        int s4 = 4 * c_start[band];
        int Kpad = c_kpad[band];
        int base = c_kbase[band];
        int K4 = 4 * w;
        int N = OUTC * Kpad;
        for (int idx = gy * 256 + tid; idx < N; idx += 32 * 256) {
            int o = idx / Kpad;
            int k = idx - o * Kpad;
            float val = 0.f;
            if (k < K4) {
                int ri = k & 1, p = k >> 1;
                int cc = (p >= w) ? 1 : 0;
                int f = p - cc * w;
                int c = s4 + ri * 2 * w + cc * w + f;
                val = W[(size_t)o * TCH + c] * gamma[c];
            }
            int slot = (k >> 3) & 7;
            int pos = (k >> 6) * 8192 + o * 64 + ((slot ^ (o & 7)) * 8) + (k & 7);
            wgP[base + pos] = f2bf(val);
        }
    }
}

// ---------------- MFMA GEMM: Y[o,t] = Wg[o,:]*h[:,t], norm fused in epilogue ----------------
// grid (32 = 8b x 4 ttile, 31 bands), 256 threads = 4 waves, each wave: M=128 x N=32
// -> 4-wave blocks fit 2/CU despite ~190 VGPR (B reg-prefetch ping-pong retained)
__global__ __launch_bounds__(256) void gemm_mfma(const float* __restrict__ x,
                                                 const unsigned short* __restrict__ wgP,
                                                 const float* __restrict__ st,
                                                 const float* __restrict__ wgam,
                                                 const float* __restrict__ wcb,
                                                 float* __restrict__ out) {
    const int band = c_order[blockIdx.y];
    const int b    = blockIdx.x >> 2;
    const int tt0  = (blockIdx.x & 3) * 128;
    const int w    = c_wid[band];
    const int s    = c_start[band];
    const int w2   = 2 * w;
    const int Kpad = c_kpad[band];
    const int nch  = Kpad >> 6;
    const unsigned short* wgA = wgP + c_kbase[band];

    __shared__ unsigned short lA[2][8192];   // 2 x 16KB: [o=128][k=64], slot-swizzled

    const int tid  = threadIdx.x;
    const int lane = tid & 63;
    const int wv   = tid >> 6;          // wave id (0..3) -> t-block of 32
    const int l15  = lane & 15;
    const int lg   = lane >> 4;         // 0..3

    const float* xb = x + (size_t)b * (CCH * FF * TTS * 2);
    // per-lane t column (float index) for B loads: t = tt0 + wv*32 + nf*16 + l15
    const float* colbase = xb + (size_t)(tt0 + wv * 32 + l15) * 2;

    f32x4 acc[8][2] = {};
    float2 bA[16], bB[16];

    // issue 16 float2 loads of chunk c's B tile into dst (row clamped: A-zeros kill junk)
#define LOADB(c, dst) do {                                                     \
    _Pragma("unroll")                                                          \
    for (int kk = 0; kk < 2; ++kk)                                             \
        _Pragma("unroll")                                                      \
        for (int nf = 0; nf < 2; ++nf)                                         \
            _Pragma("unroll")                                                  \
            for (int j = 0; j < 4; ++j) {                                      \
                int p = 32 * (c) + 16 * kk + 4 * lg + j;                       \
                p = min(p, w2 - 1);                                            \
                int row = s + p + ((p >= w) ? (FF - w) : 0);                   \
                dst[kk * 8 + nf * 4 + j] =                                     \
                    *(const float2*)(colbase + (size_t)row * 1024 + nf * 32);  \
            }                                                                  \
} while (0)

    // stage chunk c's A panel into LDS buffer buf (16KB via global_load_lds dwordx4)
#define STAGE(c, buf) do {                                                     \
    const unsigned short* srcc = wgA + (size_t)(c) * 8192;                     \
    _Pragma("unroll")                                                          \
    for (int q = 0; q < 4; ++q)                                                \
        gload_lds16(srcc + q * 2048 + tid * 8, &lA[buf][q * 2048 + tid * 8]);  \
} while (0)

    // cvt + 32 MFMA on chunk whose B regs are in br and A panel in lA[buf]
#define COMPUTE(br, buf) do {                                                  \
    _Pragma("unroll")                                                          \
    for (int kk = 0; kk < 2; ++kk) {                                           \
        short8 af[8];                                                          \
        _Pragma("unroll")                                                      \
        for (int m = 0; m < 8; ++m) {                                          \
            int o = m * 16 + l15;                                              \
            int slot = (lg + 4 * kk) ^ (o & 7);                                \
            af[m] = *(const short8*)&lA[buf][o * 64 + slot * 8];               \
        }                                                                      \
        _Pragma("unroll")                                                      \
        for (int nf = 0; nf < 2; ++nf) {                                       \
            short8 bf;                                                         \
            _Pragma("unroll")                                                  \
            for (int j = 0; j < 4; ++j) {                                      \
                float2 v = br[kk * 8 + nf * 4 + j];                            \
                bf[2 * j]     = (short)f2bf(v.x);                              \
                bf[2 * j + 1] = (short)f2bf(v.y);                              \
            }                                                                  \
            _Pragma("unroll")                                                  \
            for (int m = 0; m < 8; ++m)                                        \
                acc[m][nf] = __builtin_amdgcn_mfma_f32_16x16x32_bf16(          \
                    af[m], bf, acc[m][nf], 0, 0, 0);                           \
        }                                                                      \
    }                                                                          \
} while (0)

    LOADB(0, bA);
    STAGE(0, 0);
    __syncthreads();
    for (int c = 0; c < nch; c += 2) {
        if (c + 1 < nch) { LOADB(c + 1, bB); STAGE(c + 1, 1); }
        COMPUTE(bA, 0);
        __syncthreads();
        if (c + 1 < nch) {
            if (c + 2 < nch) { LOADB(c + 2, bA); STAGE(c + 2, 0); }
            COMPUTE(bB, 1);
            __syncthreads();
        }
    }
#undef LOADB
#undef STAGE
#undef COMPUTE

    // inline finalize: reduce this (b,band)'s partials (<=13 chunks x 2 cc)
    float sum = 0.f, sq = 0.f;
    {
        int c0 = c_cumf[band], c1 = c_cumf[band + 1];
        for (int c = c0; c < c1; ++c) {
            const float* p0 = st + (size_t)(c * 16 + b * 2) * 2;
            sum += p0[0] + p0[2];
            sq  += p0[1] + p0[3];
        }
    }
    const float Nf = (float)(w * 2048);    // 4*w*512
    const float mu = sum / Nf;
    const float rs = rsqrtf(sq / Nf - mu * mu + EPSV);

#pragma unroll
    for (int m = 0; m < 8; ++m) {
#pragma unroll
        for (int r = 0; r < 4; ++r) {
            int o = m * 16 + lg * 4 + r;
            float wg = wgam[band * OUTC + o];
            float cb = wcb[band * OUTC + o];
            size_t rowoff = (((size_t)b * OUTC + o) * NBANDS + band) * TTS;
#pragma unroll
            for (int nf = 0; nf < 2; ++nf) {
                int t = tt0 + wv * 32 + nf * 16 + l15;
                out[rowoff + t] = rs * (acc[m][nf][r] - mu * wg) + cb;
            }
        }
    }
}

extern "C" void kernel_launch(void* const* d_in, const int* in_sizes, int n_in,
                              void* d_out, int out_size, void* d_ws, size_t ws_size,
                              hipStream_t stream) {
    const float* x     = (const float*)d_in[0];
    const float* gamma = (const float*)d_in[1];
    const float* beta  = (const float*)d_in[2];
    const float* W     = (const float*)d_in[3];
    const float* bias  = (const float*)d_in[4];
    float* out = (float*)d_out;
    float* ws  = (float*)d_ws;

    float* st_part = ws;            // 79*16*2 = 2528 floats (fully rewritten every call)
    float* wgam    = ws + 3072;     // 3968 floats
    float* wcb     = ws + 7168;     // 3968 floats
    unsigned short* wgP = (unsigned short*)(ws + 11264);  // 1220608 bf16 = 2.33 MB

    prep<<<NSTATS + NWPREP + NWP2, 256, 0, stream>>>(x, W, gamma, beta, bias,
                                                     st_part, wgam, wcb, wgP);
    gemm_mfma<<<dim3(32, NBANDS), 256, 0, stream>>>(x, wgP, st_part, wgam, wcb, out);
}